// Round 1
// baseline (13005.824 us; speedup 1.0000x reference)
//
#include <hip/hip_runtime.h>
#include <math.h>

// Problem dims
#define B_ 1024
#define T_ 128
#define F_ 128
#define H_ 512

// Output flat offsets (floats): (imputed, CH, h_T, XH, CH, ZH)
#define O_IMP 0
#define O_CH1 16777216
#define O_HT  33554432
#define O_XH  34078720
#define O_CH2 50855936
#define O_ZH  67633152

__device__ __forceinline__ float sigm(float x) { return 1.0f / (1.0f + __expf(-x)); }

// ws layout (floats): hdec0 [B*H] | hdec1 [B*H] | c [B*H] | cc [B*F]
__global__ __launch_bounds__(256) void init_state(float* ws) {
  int i = blockIdx.x * 256 + threadIdx.x;      // 0 .. 262143
  const int n = (B_ * H_) / 4;                 // 131072 float4 per B*H buffer
  float4 z = make_float4(0.f, 0.f, 0.f, 0.f);
  float4* w4 = (float4*)ws;
  if (i < n) w4[i] = z;                        // hdec0
  else       w4[i + n] = z;                    // c region: [2n, 3n)
}

// ---------------- Phase A: per-row chain x_h -> x_c -> z_h -> alpha -> c_h -> c_c ----------------
// grid 256 blocks x 4 rows, 256 threads: thread = (f = tid&127, rp = tid>>7 -> rows rp*2..rp*2+1)
// 256 blocks => 1 block per CU, all 256 CUs busy (was 128 blocks: half the chip idle).
__global__ __launch_bounds__(256) void rits_phaseA(
    const float* __restrict__ X, const float* __restrict__ MM, const float* __restrict__ D,
    const float* __restrict__ W_gx, const float* __restrict__ b_gx,
    const float* __restrict__ W_hist, const float* __restrict__ b_hist,
    const float* __restrict__ W_feat, const float* __restrict__ b_feat,
    const float* __restrict__ W_comb, const float* __restrict__ b_comb,
    const float* __restrict__ hdec, float* __restrict__ cc_ws,
    float* __restrict__ out, int t)
{
  __shared__ float hds[4][516];    // h_dec rows (pitch 516: 2064B, 16B-aligned)
  __shared__ float wch[128][68];   // weight chunk [row][64k] (pitch 68: 272B aligned)
  __shared__ float xcs[4][132];    // x_c rows
  __shared__ float gxm[4][260];    // [gamma_x | m] rows (K=256 for alpha)

  const int tid = threadIdx.x;
  const int f = tid & 127;
  const int rp = tid >> 7;
  const int r0 = blockIdx.x * 4;

  // load h_dec rows (4 x 512 = 512 float4)
  #pragma unroll
  for (int i = 0; i < 2; ++i) {
    int f4 = tid + 256 * i;
    int row = f4 >> 7, c4 = f4 & 127;
    *(float4*)&hds[row][c4 * 4] = *(const float4*)&hdec[(r0 + row) * H_ + c4 * 4];
  }
  __syncthreads();

  // x_h = h_dec @ W_hist^T + b_hist   (K=512, 8 chunks of 64)
  float xh[2];
  { float bh = b_hist[f]; xh[0] = xh[1] = bh; }
  for (int kc = 0; kc < 8; ++kc) {
    int k0 = kc * 64;
    #pragma unroll
    for (int i = 0; i < 8; ++i) {
      int f4 = tid + 256 * i;
      int row = f4 >> 4, c4 = f4 & 15;
      *(float4*)&wch[row][c4 * 4] = *(const float4*)&W_hist[row * H_ + k0 + c4 * 4];
    }
    __syncthreads();
    #pragma unroll 4
    for (int k = 0; k < 64; k += 4) {
      float4 w = *(const float4*)&wch[f][k];
      #pragma unroll
      for (int i = 0; i < 2; ++i) {
        float4 h4 = *(const float4*)&hds[rp * 2 + i][k0 + k];
        xh[i] += w.x * h4.x + w.y * h4.y + w.z * h4.z + w.w * h4.w;
      }
    }
    __syncthreads();
  }

  // elementwise: x_c, gamma_x, stage [gamma_x|m], write XH
  float xv[2], mv[2], xcv[2];
  {
    float wgx = W_gx[f * F_ + f];
    float bgx = b_gx[f];
    #pragma unroll
    for (int i = 0; i < 2; ++i) {
      int r = rp * 2 + i;
      int idx = ((r0 + r) * T_ + t) * F_ + f;
      float x = X[idx], m = MM[idx], d = D[idx];
      xv[i] = x; mv[i] = m;
      float xc = m * x + (1.f - m) * xh[i];
      xcv[i] = xc;
      xcs[r][f] = xc;
      gxm[r][f] = __expf(-fmaxf(d * wgx + bgx, 0.f));
      gxm[r][F_ + f] = m;
      out[O_XH + idx] = xh[i];
    }
  }
  __syncthreads();

  // z_h = x_c @ Wfeat_od^T + b_feat  (full dot minus diagonal term)
  float zh[2];
  {
    float wff = W_feat[f * F_ + f];
    float bf = b_feat[f];
    #pragma unroll
    for (int i = 0; i < 2; ++i) zh[i] = bf - xcv[i] * wff;
  }
  for (int kc = 0; kc < 2; ++kc) {
    int k0 = kc * 64;
    #pragma unroll
    for (int i = 0; i < 8; ++i) {
      int f4 = tid + 256 * i;
      int row = f4 >> 4, c4 = f4 & 15;
      *(float4*)&wch[row][c4 * 4] = *(const float4*)&W_feat[row * F_ + k0 + c4 * 4];
    }
    __syncthreads();
    #pragma unroll 4
    for (int k = 0; k < 64; k += 4) {
      float4 w = *(const float4*)&wch[f][k];
      #pragma unroll
      for (int i = 0; i < 2; ++i) {
        float4 c4v = *(const float4*)&xcs[rp * 2 + i][k0 + k];
        zh[i] += w.x * c4v.x + w.y * c4v.y + w.z * c4v.z + w.w * c4v.w;
      }
    }
    __syncthreads();
  }

  // alpha = sigmoid([gamma_x|m] @ W_comb^T + b_comb)  (K=256)
  float al[2];
  { float bcb = b_comb[f];
    #pragma unroll
    for (int i = 0; i < 2; ++i) al[i] = bcb; }
  for (int kc = 0; kc < 4; ++kc) {
    int k0 = kc * 64;
    #pragma unroll
    for (int i = 0; i < 8; ++i) {
      int f4 = tid + 256 * i;
      int row = f4 >> 4, c4 = f4 & 15;
      *(float4*)&wch[row][c4 * 4] = *(const float4*)&W_comb[row * 256 + k0 + c4 * 4];
    }
    __syncthreads();
    #pragma unroll 4
    for (int k = 0; k < 64; k += 4) {
      float4 w = *(const float4*)&wch[f][k];
      #pragma unroll
      for (int i = 0; i < 2; ++i) {
        float4 g4 = *(const float4*)&gxm[rp * 2 + i][k0 + k];
        al[i] += w.x * g4.x + w.y * g4.y + w.z * g4.z + w.w * g4.w;
      }
    }
    __syncthreads();
  }

  // c_h, c_c (== imputed), outputs
  #pragma unroll
  for (int i = 0; i < 2; ++i) {
    int r = rp * 2 + i;
    int idx = ((r0 + r) * T_ + t) * F_ + f;
    float a = sigm(al[i]);
    float ch = a * zh[i] + (1.f - a) * xh[i];
    float cc = mv[i] * xv[i] + (1.f - mv[i]) * ch;
    out[O_IMP + idx] = cc;
    out[O_CH1 + idx] = ch;
    out[O_CH2 + idx] = ch;
    out[O_ZH  + idx] = zh[i];
    cc_ws[(r0 + r) * F_ + f] = cc;
  }
}

// ---------------- Phase B: gates GEMM (K=768) + LSTM + fused gamma_h[t+1]*decay ----------------
// grid (16,16): 64-row tile x 32-hcol tile (=> 128 gate cols: i/f/g/o quadrants)
// threads 256: tx=tid&31 -> cols 4tx..4tx+3; ty=tid>>5 -> rows 8ty..8ty+7
__global__ __launch_bounds__(256) void rits_phaseB(
    const float* __restrict__ MM, const float* __restrict__ D,
    const float* __restrict__ W_gh, const float* __restrict__ b_gh,
    const float* __restrict__ W_ih, const float* __restrict__ W_hh,
    const float* __restrict__ b_ih, const float* __restrict__ b_hh,
    const float* __restrict__ cc_ws, const float* __restrict__ hdec_in,
    float* __restrict__ hdec_out, float* __restrict__ c_ws,
    float* __restrict__ out, int t)
{
  __shared__ float Ash[32][68];     // A chunk, [k][row]
  __shared__ float Wsh[32][132];    // W chunk, [k][col]
  __shared__ float gsh[64][132];    // gates tile; reused for d[t+1] tile
  __shared__ float wgsh[32][132];   // W_gh rows for this hcol tile (padded pitch vs bank conflict)

  const int tid = threadIdx.x;
  const int tx = tid & 31, ty = tid >> 5;
  const int r0 = blockIdx.x * 64;
  const int c0 = blockIdx.y * 32;

  // stage W_gh tile (32 hcols x 128)
  #pragma unroll
  for (int i = 0; i < 4; ++i) {
    int f4 = tid + 256 * i;               // 1024 float4
    int hr = f4 >> 5, c4 = f4 & 31;
    *(float4*)&wgsh[hr][c4 * 4] = *(const float4*)&W_gh[(c0 + hr) * F_ + c4 * 4];
  }

  float acc[8][4];
  #pragma unroll
  for (int i = 0; i < 8; ++i)
    #pragma unroll
    for (int j = 0; j < 4; ++j) acc[i][j] = 0.f;

  for (int kc = 0; kc < 24; ++kc) {
    const int k0 = kc * 32;
    // A chunk: row r = tid>>2, k-subrange kq = (tid&3)*8
    {
      int r = tid >> 2;
      int kq = (tid & 3) * 8;
      float4 v0, v1;
      if (k0 < 128) {            // c_c
        const float* p = &cc_ws[(r0 + r) * F_ + k0 + kq];
        v0 = *(const float4*)p; v1 = *(const float4*)(p + 4);
      } else if (k0 < 256) {     // m
        const float* p = &MM[((r0 + r) * T_ + t) * F_ + (k0 - 128) + kq];
        v0 = *(const float4*)p; v1 = *(const float4*)(p + 4);
      } else {                   // h_dec
        const float* p = &hdec_in[(r0 + r) * H_ + (k0 - 256) + kq];
        v0 = *(const float4*)p; v1 = *(const float4*)(p + 4);
      }
      float at[8] = {v0.x, v0.y, v0.z, v0.w, v1.x, v1.y, v1.z, v1.w};
      #pragma unroll
      for (int j = 0; j < 8; ++j) Ash[kq + j][r] = at[j];
    }
    // W chunk: col = tid>>1 (0..127), kq = (tid&1)*16
    {
      int col = tid >> 1;
      int kq = (tid & 1) * 16;
      int g = (col >> 5) * H_ + c0 + (col & 31);   // gate row index in [0,2048)
      const float* p = (k0 < 256) ? &W_ih[g * 256 + k0 + kq]
                                  : &W_hh[g * H_ + (k0 - 256) + kq];
      float4 w0 = *(const float4*)p;
      float4 w1 = *(const float4*)(p + 4);
      float4 w2 = *(const float4*)(p + 8);
      float4 w3 = *(const float4*)(p + 12);
      float wt[16] = {w0.x, w0.y, w0.z, w0.w, w1.x, w1.y, w1.z, w1.w,
                      w2.x, w2.y, w2.z, w2.w, w3.x, w3.y, w3.z, w3.w};
      #pragma unroll
      for (int j = 0; j < 16; ++j) Wsh[kq + j][col] = wt[j];
    }
    __syncthreads();
    #pragma unroll 4
    for (int kk = 0; kk < 32; ++kk) {
      const float4 a0 = *(const float4*)&Ash[kk][8 * ty];
      const float4 a1 = *(const float4*)&Ash[kk][8 * ty + 4];
      const float4 w  = *(const float4*)&Wsh[kk][4 * tx];
      const float av[8] = {a0.x, a0.y, a0.z, a0.w, a1.x, a1.y, a1.z, a1.w};
      #pragma unroll
      for (int i = 0; i < 8; ++i) {
        acc[i][0] = fmaf(av[i], w.x, acc[i][0]);
        acc[i][1] = fmaf(av[i], w.y, acc[i][1]);
        acc[i][2] = fmaf(av[i], w.z, acc[i][2]);
        acc[i][3] = fmaf(av[i], w.w, acc[i][3]);
      }
    }
    __syncthreads();
  }

  // add biases, park gates in LDS for quadrant exchange
  #pragma unroll
  for (int j = 0; j < 4; ++j) {
    int cl = 4 * tx + j;
    int g = (cl >> 5) * H_ + c0 + (cl & 31);
    float bia = b_ih[g] + b_hh[g];
    #pragma unroll
    for (int i = 0; i < 8; ++i) gsh[8 * ty + i][cl] = acc[i][j] + bia;
  }
  __syncthreads();

  // LSTM update: thread = (hl = tid&31, rg = tid>>5 -> rows 8rg..8rg+7)
  const int hl = tid & 31;
  const int rg = tid >> 5;
  float hnew[8];
  #pragma unroll
  for (int i = 0; i < 8; ++i) {
    int r = 8 * rg + i;
    float ig = gsh[r][hl];
    float fg = gsh[r][32 + hl];
    float gg = gsh[r][64 + hl];
    float og = gsh[r][96 + hl];
    int cidx = (r0 + r) * H_ + c0 + hl;
    float cn = sigm(fg) * c_ws[cidx] + sigm(ig) * tanhf(gg);
    c_ws[cidx] = cn;
    hnew[i] = sigm(og) * tanhf(cn);
  }
  __syncthreads();

  if (t == T_ - 1) {
    #pragma unroll
    for (int i = 0; i < 8; ++i) {
      int r = 8 * rg + i;
      out[O_HT + (r0 + r) * H_ + c0 + hl] = hnew[i];
    }
  } else {
    // stage d[:, t+1, :] tile into gsh (reuse), then gamma_h[t+1] and decay
    #pragma unroll
    for (int i = 0; i < 8; ++i) {
      int f4 = tid + 256 * i;              // 2048 float4
      int r = f4 >> 5, c4 = f4 & 31;
      *(float4*)&gsh[r][c4 * 4] = *(const float4*)&D[((r0 + r) * T_ + (t + 1)) * F_ + c4 * 4];
    }
    __syncthreads();
    float bg = b_gh[c0 + hl];
    float dot0[8];
    #pragma unroll
    for (int i = 0; i < 8; ++i) dot0[i] = 0.f;
    for (int kb = 0; kb < 128; kb += 16) {
      const float4 w0 = *(const float4*)&wgsh[hl][kb];
      const float4 w1 = *(const float4*)&wgsh[hl][kb + 4];
      const float4 w2 = *(const float4*)&wgsh[hl][kb + 8];
      const float4 w3 = *(const float4*)&wgsh[hl][kb + 12];
      #pragma unroll
      for (int i = 0; i < 8; ++i) {
        const float* dr = &gsh[8 * rg + i][kb];
        const float4 d0 = *(const float4*)dr;
        const float4 d1 = *(const float4*)(dr + 4);
        const float4 d2 = *(const float4*)(dr + 8);
        const float4 d3 = *(const float4*)(dr + 12);
        dot0[i] += w0.x * d0.x + w0.y * d0.y + w0.z * d0.z + w0.w * d0.w
                 + w1.x * d1.x + w1.y * d1.y + w1.z * d1.z + w1.w * d1.w
                 + w2.x * d2.x + w2.y * d2.y + w2.z * d2.z + w2.w * d2.w
                 + w3.x * d3.x + w3.y * d3.y + w3.z * d3.z + w3.w * d3.w;
      }
    }
    #pragma unroll
    for (int i = 0; i < 8; ++i) {
      int r = 8 * rg + i;
      float gam = __expf(-fmaxf(dot0[i] + bg, 0.f));
      hdec_out[(r0 + r) * H_ + c0 + hl] = hnew[i] * gam;
    }
  }
}

extern "C" void kernel_launch(void* const* d_in, const int* in_sizes, int n_in,
                              void* d_out, int out_size, void* d_ws, size_t ws_size,
                              hipStream_t stream) {
  const float* X      = (const float*)d_in[0];
  const float* MM     = (const float*)d_in[1];
  const float* D      = (const float*)d_in[2];
  const float* W_gh   = (const float*)d_in[3];
  const float* b_gh   = (const float*)d_in[4];
  const float* W_gx   = (const float*)d_in[5];
  const float* b_gx   = (const float*)d_in[6];
  const float* W_hist = (const float*)d_in[7];
  const float* b_hist = (const float*)d_in[8];
  const float* W_feat = (const float*)d_in[9];
  const float* b_feat = (const float*)d_in[10];
  const float* W_comb = (const float*)d_in[11];
  const float* b_comb = (const float*)d_in[12];
  const float* W_ih   = (const float*)d_in[13];
  const float* W_hh   = (const float*)d_in[14];
  const float* b_ih   = (const float*)d_in[15];
  const float* b_hh   = (const float*)d_in[16];

  float* out = (float*)d_out;
  float* ws = (float*)d_ws;
  float* hd0 = ws;                       // h_dec ping
  float* hd1 = ws + B_ * H_;             // h_dec pong
  float* cst = ws + 2 * B_ * H_;         // c state
  float* ccb = ws + 3 * B_ * H_;         // c_c buffer

  init_state<<<dim3(1024), dim3(256), 0, stream>>>(ws);

  for (int t = 0; t < T_; ++t) {
    float* hin  = (t & 1) ? hd1 : hd0;
    float* hout = (t & 1) ? hd0 : hd1;
    rits_phaseA<<<dim3(256), dim3(256), 0, stream>>>(
        X, MM, D, W_gx, b_gx, W_hist, b_hist, W_feat, b_feat, W_comb, b_comb,
        hin, ccb, out, t);
    rits_phaseB<<<dim3(16, 16), dim3(256), 0, stream>>>(
        MM, D, W_gh, b_gh, W_ih, W_hh, b_ih, b_hh,
        ccb, hin, hout, cst, out, t);
  }
}